// Round 11
// baseline (90.133 us; speedup 1.0000x reference)
//
#include <hip/hip_runtime.h>
#include <hip/hip_bf16.h>

#define NBS 8
#define NT 32
#define NF 128
#define NDIN 64
#define NNH 8
#define NDOUT 64

typedef __bf16 bf16_t;
typedef __bf16 bf16x8 __attribute__((ext_vector_type(8)));
typedef float f32x4 __attribute__((ext_vector_type(4)));

// ---------------- kernel 1: q/k projection ----------------
// One wave per (t,f): q[b,he] = sum_d X[b,f,t,d] * Wq[t,f,d,he], all 8 b at once.
// Wq/Wk/X each read exactly once from HBM -> ~46MB -> memory-bound ~8us.
__global__ __launch_bounds__(256, 4)
void qk_project_kernel(const float* __restrict__ X,
                       const float* __restrict__ Wq,
                       const float* __restrict__ Wk,
                       float* __restrict__ q_ws,
                       float* __restrict__ k_ws)
{
    __shared__ float lx[4][8][64];
    const int w = threadIdx.x >> 6, lane = threadIdx.x & 63;
    const int gw = blockIdx.x * 4 + w;
    const int t = gw >> 7, f = gw & 127;

    {
        const int b = lane >> 3, d8 = (lane & 7) << 3;
        const float* src = &X[(((size_t)b * NF + f) * NT + t) * NDIN + d8];
        const float4 v0 = *(const float4*)src;
        const float4 v1 = *(const float4*)(src + 4);
        *(float4*)&lx[w][b][d8]     = v0;
        *(float4*)&lx[w][b][d8 + 4] = v1;
    }
    __syncthreads();

    const int dq = lane >> 4, he = lane & 15;
    const float* wq = Wq + ((size_t)t * NF + f) * (NDIN * 16);
    const float* wk = Wk + ((size_t)t * NF + f) * (NDIN * 16);
    float qa[8] = {0,0,0,0,0,0,0,0}, ka[8] = {0,0,0,0,0,0,0,0};
    for (int d0 = 0; d0 < NDIN; d0 += 4) {
        const int d = d0 + dq;
        const float wqv = wq[d * 16 + he];
        const float wkv = wk[d * 16 + he];
#pragma unroll
        for (int b = 0; b < 8; ++b) {
            const float x = lx[w][b][d];
            qa[b] = fmaf(x, wqv, qa[b]);
            ka[b] = fmaf(x, wkv, ka[b]);
        }
    }
#pragma unroll
    for (int b = 0; b < 8; ++b) {
        qa[b] += __shfl_xor(qa[b], 16); qa[b] += __shfl_xor(qa[b], 32);
        ka[b] += __shfl_xor(ka[b], 16); ka[b] += __shfl_xor(ka[b], 32);
    }
#pragma unroll
    for (int bb = 0; bb < 2; ++bb) {
        const int b = dq + bb * 4;
        q_ws[(((size_t)b * NT + t) * 16 + he) * NF + f] = qa[b];
        k_ws[(((size_t)b * NT + t) * 16 + he) * NF + f] = ka[b];
    }
}

// ---------------- kernel 2: attention + output GEMMs ----------------
// Grid 512 = (b, t, hg): block does heads hg*4..hg*4+3 for all 128 f.
// 512 thr = 8 waves, wave w = row-tile rt. Structure and all GEMM/epilogue
// code VERBATIM from passing r9. Register diet (r9: 104 regs, 1 block/CU):
// two-pass scores keep only rowmax (saves sc[32]); pass 2 packs
// UNNORMALIZED e to pf[4] bf16x8 (16 regs); after the sum reduce, pf is
// normalized IN PLACE with the lane's OWN rinv (A-frag row = cq = the
// lane's own row -> same semantics as r9's pre-MFMA normalize; r10's
// cross-lane rowscale shuffle is dropped entirely). Est ~88 regs ->
// 2 blocks/CU resident (16 waves = 4 waves/SIMD).
// LAUNCH BOUNDS RULE (r4/r5/r8): 2nd arg >=4 forces 64-VGPR bucket + spills;
// (512,2) is the proven-safe bound.
__global__ __launch_bounds__(512, 2)
void spatial_attn_kernel(const float* __restrict__ X,
                         const float* __restrict__ q_ws,
                         const float* __restrict__ k_ws,
                         const float* __restrict__ Wkey,
                         const float* __restrict__ U,
                         const float* __restrict__ AC,
                         const float* __restrict__ Alpha,
                         const float* __restrict__ Wo,
                         const float* __restrict__ Bias,
                         float* __restrict__ Out)
{
    const int blk  = blockIdx.x;
    const int b    = blk & 7;          // 8 consecutive blocks share (t,hg): Wo/U slices L2-hot
    const int tq   = blk >> 3;
    const int hg   = tq & 1;
    const int t    = tq >> 1;
    const int tid  = threadIdx.x;
    const int w    = tid >> 6;
    const int lane = tid & 63;
    const int cq   = lane & 15;
    const int rq   = lane >> 4;
    const int rt   = w;                // row tile 0..7
    const int frow = 16 * rt + cq;

    // LDS carve: 62992 B (2 blocks/CU = 125984 <= 163840)
    __shared__ __align__(16) unsigned char smem[62992];
    bf16_t* XTs        = (bf16_t*)smem;                      // 16384: (d,l) -> d*128 + (((l>>3)^(d&15))<<3) + (l&7)
    float4 (*kv)[136]  = (float4 (*)[136])(smem + 16384);    // 8704: {k0,k1,u0,u1}(th,l), slot 17*(l>>4)+(l&15)
    float2 (*qls)[128] = (float2 (*)[128])(smem + 25088);    // 4096: {q0,q1}(th,f)
    float*  acs        = (float*)(smem + 29184);             // 16
    bf16_t* WTs        = (bf16_t*)(smem + 29200);            // 16384: buf*4096 + o*64 + (((d>>3)^(o&7))<<3) + (d&7)
    bf16_t (*Vscr)[16][68] = (bf16_t (*)[16][68])(smem + 45584); // 17408

    // ---- stage XT (X^T bf16, XOR-swizzled) ----
#pragma unroll
    for (int r = 0; r < 4; ++r) {
        const int idx = tid + r * 512;
        const int f = idx >> 4, d4 = (idx & 15) << 2;
        const float4 v = *(const float4*)&X[(((size_t)b * NF + f) * NT + t) * NDIN + d4];
        float vv[4]; vv[0] = v.x; vv[1] = v.y; vv[2] = v.z; vv[3] = v.w;
#pragma unroll
        for (int i = 0; i < 4; ++i) {
            const int d = d4 + i;
            XTs[d * 128 + (((f >> 3) ^ (d & 15)) << 3) + (f & 7)] = (bf16_t)vv[i];
        }
    }
    // ---- stage kv, qls (this block's 4 heads), acs ----
    {
        const int hh = tid >> 7, l = tid & 127;
        const int h = hg * 4 + hh;
        const size_t qkb = ((size_t)b * NT + t) * 16;
        const float k0 = k_ws[(qkb + 2 * h + 0) * NF + l];
        const float k1 = k_ws[(qkb + 2 * h + 1) * NF + l];
        const float2 u01 = *(const float2*)&U[((size_t)t * NF + l) * 2];
        kv[hh][17 * (l >> 4) + (l & 15)] = make_float4(k0, k1, u01.x, u01.y);
        const float q0 = q_ws[(qkb + 2 * h + 0) * NF + l];
        const float q1 = q_ws[(qkb + 2 * h + 1) * NF + l];
        qls[hh][l] = make_float2(q0, q1);
    }
    if (tid < 4) acs[tid] = AC[t * NNH + hg * 4 + tid];
    // ---- stage WT for first head into buf 0 ----
#pragma unroll
    for (int r = 0; r < 2; ++r) {
        const int idx = tid + r * 512;
        const int dd = idx >> 4, o4 = (idx & 15) << 2;
        const float4 v = *(const float4*)&Wo[((size_t)t * 512 + (hg * 4) * 64 + dd) * NDOUT + o4];
        float vv[4]; vv[0] = v.x; vv[1] = v.y; vv[2] = v.z; vv[3] = v.w;
#pragma unroll
        for (int i = 0; i < 4; ++i) {
            const int o = o4 + i;
            WTs[o * 64 + (((dd >> 3) ^ (o & 7)) << 3) + (dd & 7)] = (bf16_t)vv[i];
        }
    }

    const float alpha_t = Alpha[t];
    const float wk00 = Wkey[t * 4 + 0], wk01 = Wkey[t * 4 + 1];
    const float wk10 = Wkey[t * 4 + 2], wk11 = Wkey[t * 4 + 3];

    __syncthreads();   // staging complete

    f32x4 oacc[4] = { {0.f,0.f,0.f,0.f}, {0.f,0.f,0.f,0.f}, {0.f,0.f,0.f,0.f}, {0.f,0.f,0.f,0.f} };

#pragma unroll 1
    for (int th = 0; th < 4; ++th) {
        // stage WT for th+1 into the other buffer (disjoint from this head's reads)
        if (th < 3) {
            const int hn = hg * 4 + th + 1;
            const int bn = ((th + 1) & 1) * 4096;
#pragma unroll
            for (int r = 0; r < 2; ++r) {
                const int idx = tid + r * 512;
                const int dd = idx >> 4, o4 = (idx & 15) << 2;
                const float4 v = *(const float4*)&Wo[((size_t)t * 512 + hn * 64 + dd) * NDOUT + o4];
                float vv[4]; vv[0] = v.x; vv[1] = v.y; vv[2] = v.z; vv[3] = v.w;
#pragma unroll
                for (int i = 0; i < 4; ++i) {
                    const int o = o4 + i;
                    WTs[bn + o * 64 + (((dd >> 3) ^ (o & 7)) << 3) + (dd & 7)] = (bf16_t)vv[i];
                }
            }
        }
        const int buf = (th & 1) * 4096;
        const float2 qq = qls[th][frow];
        const float4 kk = kv[th][17 * (frow >> 4) + (frow & 15)];
        const float q0 = qq.x, q1 = qq.y, kf0 = kk.x, kf1 = kk.y;
        const float v1 = 2.f * alpha_t * acs[th];
        const float c0 = (q0 - alpha_t) * wk00 + (q1 + v1) * wk10;
        const float c1 = (q0 - alpha_t) * wk01 + (q1 + v1) * wk11;

        // ---- pass 1: rowmax only (no score array kept) ----
        float rowmax = -3.0e38f;
#pragma unroll
        for (int kt = 0; kt < 4; ++kt) {
            const int s  = kt * 2 + (rq >> 1);
            const int i0 = (rq & 1) << 3;
            const float4* kvp = &kv[th][17 * s + i0];
            float del = (float)(kt * 32 + rq * 8 - frow);
#pragma unroll
            for (int j = 0; j < 8; ++j) {
                const float4 kj = kvp[j];
                const float sv = q0 * kj.x + q1 * kj.y + kf0 * kj.z + kf1 * kj.w
                               + (c0 * del + c1) * del;
                rowmax = fmaxf(rowmax, sv);
                del += 1.f;
            }
        }
        rowmax = fmaxf(rowmax, __shfl_xor(rowmax, 16));
        rowmax = fmaxf(rowmax, __shfl_xor(rowmax, 32));

        // ---- pass 2: recompute, exp, pack unnormalized e to bf16 ----
        bf16x8 pf[4];
        float sum = 0.f;
#pragma unroll
        for (int kt = 0; kt < 4; ++kt) {
            const int s  = kt * 2 + (rq >> 1);
            const int i0 = (rq & 1) << 3;
            const float4* kvp = &kv[th][17 * s + i0];
            float del = (float)(kt * 32 + rq * 8 - frow);
#pragma unroll
            for (int j = 0; j < 8; ++j) {
                const float4 kj = kvp[j];
                const float sv = q0 * kj.x + q1 * kj.y + kf0 * kj.z + kf1 * kj.w
                               + (c0 * del + c1) * del;
                const float e = __expf(sv - rowmax);
                sum += e;
                pf[kt][j] = (bf16_t)e;
                del += 1.f;
            }
        }
        sum += __shfl_xor(sum, 16);
        sum += __shfl_xor(sum, 32);
        const float rinv = 1.f / sum;
        // normalize pf IN PLACE with the lane's OWN rinv (A-frag row = cq,
        // same row the lane reduced -> r9-identical semantics, no shuffle)
#pragma unroll
        for (int kt = 0; kt < 4; ++kt)
#pragma unroll
            for (int j = 0; j < 8; ++j)
                pf[kt][j] = (bf16_t)((float)pf[kt][j] * rinv);

        // ---- GEMM1 (verbatim r9): V[16x64] = P[16x128] @ X[128x64] ----
        f32x4 vacc[4] = { {0.f,0.f,0.f,0.f}, {0.f,0.f,0.f,0.f}, {0.f,0.f,0.f,0.f}, {0.f,0.f,0.f,0.f} };
#pragma unroll
        for (int kt = 0; kt < 4; ++kt) {
#pragma unroll
            for (int ct = 0; ct < 4; ++ct) {
                const bf16x8 bb = *(const bf16x8*)&XTs[(ct * 16 + cq) * 128 + (((kt * 4 + rq) ^ cq) << 3)];
                vacc[ct] = __builtin_amdgcn_mfma_f32_16x16x32_bf16(pf[kt], bb, vacc[ct], 0, 0, 0);
            }
        }
        // V C-frags -> private wave scratch (intra-wave dep only)
#pragma unroll
        for (int ct = 0; ct < 4; ++ct)
#pragma unroll
            for (int rr = 0; rr < 4; ++rr)
                Vscr[w][rq * 4 + rr][ct * 16 + cq] = (bf16_t)vacc[ct][rr];

        // ---- GEMM2 (verbatim r9): oacc += V[16x64] @ W_h[64x64] ----
#pragma unroll
        for (int kt = 0; kt < 2; ++kt) {
            const bf16x8 a = *(const bf16x8*)&Vscr[w][cq][kt * 32 + rq * 8];
#pragma unroll
            for (int ct = 0; ct < 4; ++ct) {
                const bf16x8 bw = *(const bf16x8*)&WTs[buf + (ct * 16 + cq) * 64 + (((kt * 4 + rq) ^ (cq & 7)) << 3)];
                oacc[ct] = __builtin_amdgcn_mfma_f32_16x16x32_bf16(a, bw, oacc[ct], 0, 0, 0);
            }
        }
        __syncthreads();   // next head's WT buffer ready; this buffer free for th+2
    }

    // ---- epilogue (verbatim r9): atomic combine of hg partials; hg0 carries bias ----
#pragma unroll
    for (int ct = 0; ct < 4; ++ct) {
#pragma unroll
        for (int rr = 0; rr < 4; ++rr) {
            const int f = 16 * rt + rq * 4 + rr;
            const int o = ct * 16 + cq;
            float val = oacc[ct][rr];
            if (hg == 0) val += Bias[((size_t)f * NT + t) * NDOUT + o];
            atomicAdd(&Out[(((size_t)b * NF + f) * NT + t) * NDOUT + o], val);
        }
    }
}

extern "C" void kernel_launch(void* const* d_in, const int* in_sizes, int n_in,
                              void* d_out, int out_size, void* d_ws, size_t ws_size,
                              hipStream_t stream) {
    (void)in_sizes; (void)n_in; (void)ws_size;
    const float* X    = (const float*)d_in[0];
    const float* Wq   = (const float*)d_in[1];
    const float* Wk   = (const float*)d_in[2];
    const float* Wkey = (const float*)d_in[3];
    const float* U    = (const float*)d_in[4];
    const float* AC   = (const float*)d_in[5];
    const float* Al   = (const float*)d_in[6];
    // d_in[7] = R is analytic (delta^2, delta), folded into score formula
    const float* Wo   = (const float*)d_in[8];
    const float* Bias = (const float*)d_in[9];

    float* q_ws = (float*)d_ws;                       // 2 MB
    float* k_ws = q_ws + (size_t)NBS * NT * 16 * NF;  // 2 MB

    hipMemsetAsync(d_out, 0, (size_t)out_size * sizeof(float), stream);
    qk_project_kernel<<<dim3(NT * NF / 4), dim3(256), 0, stream>>>(X, Wq, Wk, q_ws, k_ws);
    spatial_attn_kernel<<<dim3(NBS * NT * 2), dim3(512), 0, stream>>>(
        X, q_ws, k_ws, Wkey, U, AC, Al, Wo, Bias, (float*)d_out);
}

// Round 12
// 49.008 us; speedup vs baseline: 1.8391x; 1.8391x over previous
//
#include <hip/hip_runtime.h>
#include <hip/hip_bf16.h>

#define NBS 8
#define NT 32
#define NF 128
#define NDIN 64
#define NNH 8
#define NDOUT 64

typedef __bf16 bf16_t;
typedef __bf16 bf16x8 __attribute__((ext_vector_type(8)));
typedef float f32x4 __attribute__((ext_vector_type(4)));
typedef float f32x2 __attribute__((ext_vector_type(2)));

// ---------------- kernel 1: q/k projection ----------------
// One wave per (t,f): q[b,he] = sum_d X[b,f,t,d] * Wq[t,f,d,he], all 8 b at once.
// Wq/Wk/X each read exactly once from HBM -> ~46MB -> memory-bound ~8us.
__global__ __launch_bounds__(256, 4)
void qk_project_kernel(const float* __restrict__ X,
                       const float* __restrict__ Wq,
                       const float* __restrict__ Wk,
                       float* __restrict__ q_ws,
                       float* __restrict__ k_ws)
{
    __shared__ float lx[4][8][64];
    const int w = threadIdx.x >> 6, lane = threadIdx.x & 63;
    const int gw = blockIdx.x * 4 + w;
    const int t = gw >> 7, f = gw & 127;

    {
        const int b = lane >> 3, d8 = (lane & 7) << 3;
        const float* src = &X[(((size_t)b * NF + f) * NT + t) * NDIN + d8];
        const float4 v0 = *(const float4*)src;
        const float4 v1 = *(const float4*)(src + 4);
        *(float4*)&lx[w][b][d8]     = v0;
        *(float4*)&lx[w][b][d8 + 4] = v1;
    }
    __syncthreads();

    const int dq = lane >> 4, he = lane & 15;
    const float* wq = Wq + ((size_t)t * NF + f) * (NDIN * 16);
    const float* wk = Wk + ((size_t)t * NF + f) * (NDIN * 16);
    float qa[8] = {0,0,0,0,0,0,0,0}, ka[8] = {0,0,0,0,0,0,0,0};
    for (int d0 = 0; d0 < NDIN; d0 += 4) {
        const int d = d0 + dq;
        const float wqv = wq[d * 16 + he];
        const float wkv = wk[d * 16 + he];
#pragma unroll
        for (int b = 0; b < 8; ++b) {
            const float x = lx[w][b][d];
            qa[b] = fmaf(x, wqv, qa[b]);
            ka[b] = fmaf(x, wkv, ka[b]);
        }
    }
#pragma unroll
    for (int b = 0; b < 8; ++b) {
        qa[b] += __shfl_xor(qa[b], 16); qa[b] += __shfl_xor(qa[b], 32);
        ka[b] += __shfl_xor(ka[b], 16); ka[b] += __shfl_xor(ka[b], 32);
    }
#pragma unroll
    for (int bb = 0; bb < 2; ++bb) {
        const int b = dq + bb * 4;
        q_ws[(((size_t)b * NT + t) * 16 + he) * NF + f] = qa[b];
        k_ws[(((size_t)b * NT + t) * 16 + he) * NF + f] = ka[b];
    }
}

// ---------------- kernel 2: attention + output GEMMs ----------------
// REVERT to the r6/r7 winner (54.4us total): one block per (b,t), 512 thr =
// 8 waves, wave w = row-tile rt, full 8 heads per wave, WTall staged upfront,
// ONE barrier, direct epilogue (no atomics). Round-12 deltas ONLY:
//  (1) XT/WTall XOR-swizzled (r9/r11-verbatim formulas, passed twice) to kill
//      the 8-way bank conflict on B-operand ds_read_b128 (bank 4(cq+rq)%32).
//  (2) score math in packed float2 over l-pairs (kv staged SoA, 48B/pair,
//      16B-aligned, banks (16rq+12j2)%32 -> <=2-way) to enable v_pk_fma_f32.
// LAUNCH BOUNDS RULE (r4/r5/r8): 2nd arg >=4 forces the 64-VGPR bucket and
// 300MB of scratch spills; (512,2) is the proven-safe bound.
__global__ __launch_bounds__(512, 2)
void spatial_attn_kernel(const float* __restrict__ X,
                         const float* __restrict__ q_ws,
                         const float* __restrict__ k_ws,
                         const float* __restrict__ Wkey,
                         const float* __restrict__ U,
                         const float* __restrict__ AC,
                         const float* __restrict__ Alpha,
                         const float* __restrict__ Wo,
                         const float* __restrict__ Bias,
                         float* __restrict__ Out)
{
    const int blk  = blockIdx.x;
    const int b    = blk & 7;
    const int t    = blk >> 3;
    const int tid  = threadIdx.x;
    const int w    = tid >> 6;
    const int lane = tid & 63;
    const int cq   = lane & 15;
    const int rq   = lane >> 4;
    const int rt   = w;                // row tile 0..7
    const int frow = 16 * rt + cq;

    // LDS carve: 140288 B (<= 160 KiB)
    __shared__ __align__(16) unsigned char smem[140288];
    bf16_t* XTs   = (bf16_t*)smem;                    // 16384: d*128 + (((f>>3)^(d&15))<<3) + (f&7)
    float*  kvf   = (float*)(smem + 16384);           // 24576: pair P of l: (h*64+P)*12 + {k0k0,k1k1,u0u0,u1u1,pad4}
    float4 (*qf)[128] = (float4 (*)[128])(smem + 40960); // 16384: {q0,q1,kf0,kf1}(h,f)
    bf16_t* WTall = (bf16_t*)(smem + 57344);          // 65536: h*4096 + o*64 + (((d>>3)^(o&7))<<3) + (d&7)
    bf16_t (*Vscr)[16][68] = (bf16_t (*)[16][68])(smem + 122880); // 17408

    // ---- stage XT (X^T bf16, XOR-swizzled; r9-verbatim) ----
#pragma unroll
    for (int r = 0; r < 4; ++r) {
        const int idx = tid + r * 512;
        const int f = idx >> 4, d4 = (idx & 15) << 2;
        const float4 v = *(const float4*)&X[(((size_t)b * NF + f) * NT + t) * NDIN + d4];
        float vv[4]; vv[0] = v.x; vv[1] = v.y; vv[2] = v.z; vv[3] = v.w;
#pragma unroll
        for (int i = 0; i < 4; ++i) {
            const int d = d4 + i;
            XTs[d * 128 + (((f >> 3) ^ (d & 15)) << 3) + (f & 7)] = (bf16_t)vv[i];
        }
    }
    // ---- stage qf + kvf: one thread per (h,l), 2 reps ----
#pragma unroll
    for (int r = 0; r < 2; ++r) {
        const int idx = tid + r * 512;
        const int hh = idx >> 7, l = idx & 127;
        const size_t qkb = ((size_t)b * NT + t) * 16;
        const float k0 = k_ws[(qkb + 2 * hh + 0) * NF + l];
        const float k1 = k_ws[(qkb + 2 * hh + 1) * NF + l];
        const float q0 = q_ws[(qkb + 2 * hh + 0) * NF + l];
        const float q1 = q_ws[(qkb + 2 * hh + 1) * NF + l];
        const float2 u01 = *(const float2*)&U[((size_t)t * NF + l) * 2];
        qf[hh][l] = make_float4(q0, q1, k0, k1);
        const int P = l >> 1, c = l & 1;
        const int base = (hh * 64 + P) * 12;
        kvf[base + 0 + c] = k0;
        kvf[base + 2 + c] = k1;
        kvf[base + 4 + c] = u01.x;
        kvf[base + 6 + c] = u01.y;
    }
    // ---- stage WTall[h] (bf16, XOR-swizzled; r9 formula + h offset) ----
#pragma unroll
    for (int rep = 0; rep < 16; ++rep) {
        const int flat = rep * 512 + tid;              // 0..8191
        const int h = flat >> 10, f10 = flat & 1023;
        const int dd = f10 >> 4, o4 = (f10 & 15) << 2;
        const float4 v = *(const float4*)&Wo[((size_t)t * 512 + h * 64 + dd) * NDOUT + o4];
        float vv[4]; vv[0] = v.x; vv[1] = v.y; vv[2] = v.z; vv[3] = v.w;
#pragma unroll
        for (int i = 0; i < 4; ++i) {
            const int o = o4 + i;
            WTall[h * 4096 + o * 64 + (((dd >> 3) ^ (o & 7)) << 3) + (dd & 7)] = (bf16_t)vv[i];
        }
    }

    const float alpha_t = Alpha[t];
    const float wk00 = Wkey[t * 4 + 0], wk01 = Wkey[t * 4 + 1];
    const float wk10 = Wkey[t * 4 + 2], wk11 = Wkey[t * 4 + 3];

    __syncthreads();   // the ONLY barrier

    f32x4 oacc[4] = { {0.f,0.f,0.f,0.f}, {0.f,0.f,0.f,0.f}, {0.f,0.f,0.f,0.f}, {0.f,0.f,0.f,0.f} };

#pragma unroll 1
    for (int h = 0; h < NNH; ++h) {
        const float4 qq = qf[h][frow];             // {q0,q1,kf0,kf1}
        const float q0 = qq.x, q1 = qq.y, kf0 = qq.z, kf1 = qq.w;
        const float v1 = 2.f * alpha_t * AC[t * NNH + h];
        const float c0 = (q0 - alpha_t) * wk00 + (q1 + v1) * wk10;
        const float c1 = (q0 - alpha_t) * wk01 + (q1 + v1) * wk11;

        // ---- scores, packed float2 over l-pairs: sc2[kt][j2] = S[frow][l0..l0+1]
        f32x2 sc2[4][4];
        f32x2 mx2 = { -3.0e38f, -3.0e38f };
#pragma unroll
        for (int kt = 0; kt < 4; ++kt) {
#pragma unroll
            for (int j2 = 0; j2 < 4; ++j2) {
                const int P = kt * 16 + rq * 4 + j2;
                const float4 ld0 = *(const float4*)&kvf[(h * 64 + P) * 12];
                const float4 ld1 = *(const float4*)&kvf[(h * 64 + P) * 12 + 4];
                const f32x2 k0p = { ld0.x, ld0.y };
                const f32x2 k1p = { ld0.z, ld0.w };
                const f32x2 u0p = { ld1.x, ld1.y };
                const f32x2 u1p = { ld1.z, ld1.w };
                const float l0 = (float)(kt * 32 + rq * 8 + 2 * j2 - frow);
                const f32x2 delp = { l0, l0 + 1.f };
                f32x2 sv = k0p * q0 + k1p * q1 + u0p * kf0 + u1p * kf1
                         + (delp * c0 + c1) * delp;
                sc2[kt][j2] = sv;
                mx2 = __builtin_elementwise_max(mx2, sv);
            }
        }
        float rowmax = fmaxf(mx2.x, mx2.y);
        rowmax = fmaxf(rowmax, __shfl_xor(rowmax, 16));
        rowmax = fmaxf(rowmax, __shfl_xor(rowmax, 32));
        f32x2 s2 = { 0.f, 0.f };
#pragma unroll
        for (int kt = 0; kt < 4; ++kt)
#pragma unroll
            for (int j2 = 0; j2 < 4; ++j2) {
                f32x2 sv = sc2[kt][j2];
                const f32x2 e = { __expf(sv.x - rowmax), __expf(sv.y - rowmax) };
                s2 += e;
                sc2[kt][j2] = e;
            }
        float sum = s2.x + s2.y;
        sum += __shfl_xor(sum, 16);
        sum += __shfl_xor(sum, 32);
        const float rinv = 1.f / sum;

        // ---- GEMM1: V[16x64] = P[16x128] @ X[128x64]; P normalized pre-MFMA ----
        f32x4 vacc[4] = { {0.f,0.f,0.f,0.f}, {0.f,0.f,0.f,0.f}, {0.f,0.f,0.f,0.f}, {0.f,0.f,0.f,0.f} };
#pragma unroll
        for (int kt = 0; kt < 4; ++kt) {
            bf16x8 pf;
#pragma unroll
            for (int j2 = 0; j2 < 4; ++j2) {
                const f32x2 e = sc2[kt][j2];
                pf[2 * j2 + 0] = (bf16_t)(e.x * rinv);
                pf[2 * j2 + 1] = (bf16_t)(e.y * rinv);
            }
#pragma unroll
            for (int ct = 0; ct < 4; ++ct) {
                const bf16x8 bb = *(const bf16x8*)&XTs[(ct * 16 + cq) * 128 + (((kt * 4 + rq) ^ cq) << 3)];
                vacc[ct] = __builtin_amdgcn_mfma_f32_16x16x32_bf16(pf, bb, vacc[ct], 0, 0, 0);
            }
        }
        // V C-frags -> private wave scratch (intra-wave dep only, no barrier)
#pragma unroll
        for (int ct = 0; ct < 4; ++ct)
#pragma unroll
            for (int rr = 0; rr < 4; ++rr)
                Vscr[w][rq * 4 + rr][ct * 16 + cq] = (bf16_t)vacc[ct][rr];

        // ---- GEMM2: oacc += V[16x64] @ W_h[64x64] ----
#pragma unroll
        for (int kt = 0; kt < 2; ++kt) {
            const bf16x8 a = *(const bf16x8*)&Vscr[w][cq][kt * 32 + rq * 8];
#pragma unroll
            for (int ct = 0; ct < 4; ++ct) {
                const bf16x8 bw = *(const bf16x8*)&WTall[h * 4096 + (ct * 16 + cq) * 64 + (((kt * 4 + rq) ^ (cq & 7)) << 3)];
                oacc[ct] = __builtin_amdgcn_mfma_f32_16x16x32_bf16(a, bw, oacc[ct], 0, 0, 0);
            }
        }
    }

    // ---- epilogue: Out = oacc + bias (all 8 heads complete per wave) ----
#pragma unroll
    for (int ct = 0; ct < 4; ++ct) {
#pragma unroll
        for (int rr = 0; rr < 4; ++rr) {
            const int f = 16 * rt + rq * 4 + rr;
            const int o = ct * 16 + cq;
            Out[(((size_t)b * NF + f) * NT + t) * NDOUT + o] =
                oacc[ct][rr] + Bias[((size_t)f * NT + t) * NDOUT + o];
        }
    }
}

extern "C" void kernel_launch(void* const* d_in, const int* in_sizes, int n_in,
                              void* d_out, int out_size, void* d_ws, size_t ws_size,
                              hipStream_t stream) {
    (void)in_sizes; (void)n_in; (void)ws_size; (void)out_size;
    const float* X    = (const float*)d_in[0];
    const float* Wq   = (const float*)d_in[1];
    const float* Wk   = (const float*)d_in[2];
    const float* Wkey = (const float*)d_in[3];
    const float* U    = (const float*)d_in[4];
    const float* AC   = (const float*)d_in[5];
    const float* Al   = (const float*)d_in[6];
    // d_in[7] = R is analytic (delta^2, delta), folded into score formula
    const float* Wo   = (const float*)d_in[8];
    const float* Bias = (const float*)d_in[9];

    float* q_ws = (float*)d_ws;                       // 2 MB
    float* k_ws = q_ws + (size_t)NBS * NT * 16 * NF;  // 2 MB

    qk_project_kernel<<<dim3(NT * NF / 4), dim3(256), 0, stream>>>(X, Wq, Wk, q_ws, k_ws);
    spatial_attn_kernel<<<dim3(NBS * NT), dim3(512), 0, stream>>>(
        X, q_ws, k_ws, Wkey, U, AC, Al, Wo, Bias, (float*)d_out);
}